// Round 10
// baseline (160.554 us; speedup 1.0000x reference)
//
#include <hip/hip_runtime.h>
#include <math.h>

#define N_PTS   65536
#define N_CTR   1024       // per set
#define NCELLS  256        // 16x16 Morton cells
#define NSLICE  64         // 64 slices x 1024 sorted points
#define CUT     40.0f      // cull threshold (log2 units): e < 2^-40 dropped
#define LOG2E   1.4426950408889634f

#if __has_builtin(__builtin_amdgcn_exp2f)
#define EXP2(v) __builtin_amdgcn_exp2f(v)
#else
#define EXP2(v) exp2f(v)
#endif

__device__ __forceinline__ int morton4(int v) {
    v = (v | (v << 2)) & 0x33;
    v = (v | (v << 1)) & 0x55;
    return v;
}
__device__ __forceinline__ int cell_of(float2 p) {
    int cx = (int)(p.x * 16.f); cx = cx > 15 ? 15 : (cx < 0 ? 0 : cx);
    int cy = (int)(p.y * 16.f); cy = cy > 15 ? 15 : (cy < 0 ? 0 : cy);
    return morton4(cx) | (morton4(cy) << 1);
}

// K1: fold per-center constants + count points per Morton cell.
__global__ __launch_bounds__(256) void prep_kernel(
    const float* __restrict__ x,
    const float* __restrict__ h0, const float* __restrict__ c0, const float* __restrict__ w0,
    const float* __restrict__ h1, const float* __restrict__ c1, const float* __restrict__ w1,
    const float* __restrict__ h2, const float* __restrict__ c2, const float* __restrict__ w2,
    float4* __restrict__ RA, float4* __restrict__ RB, float* __restrict__ RC,
    float4* __restrict__ RT, unsigned int* __restrict__ cnt)
{
    const int idx = blockIdx.x * 256 + threadIdx.x;   // 0..65535
    {
        float2 p = ((const float2*)x)[idx];
        atomicAdd(&cnt[cell_of(p)], 1u);
    }
    if (idx >= 3 * N_CTR) return;

    const int set = idx >> 10;
    const int j   = idx & (N_CTR - 1);
    const float*  h = (set == 0) ? h0 : ((set == 1) ? h1 : h2);
    const float2* c = (const float2*)((set == 0) ? c0 : ((set == 1) ? c1 : c2));
    const float2* w = (const float2*)((set == 0) ? w0 : ((set == 1) ? w1 : w2));

    float2 cj = c[j];
    float2 wj = w[j];
    float  hh = h[j];
    float d1 = wj.x * wj.x;
    float d2 = wj.y * wj.y;
    float zb =  2.f * cj.x * d1 * LOG2E;
    float zc = -d1 * LOG2E;
    float zd =  2.f * cj.y * d2 * LOG2E;
    float ze = -d2 * LOG2E;
    float za = -(cj.x * cj.x * d1 + cj.y * cj.y * d2) * LOG2E;
    float k0, k1, k2, k3;
    if (set == 0) {
        k0 = -2.f * hh * d1;  k1 = 2.f * hh * d1 * cj.x;
        k2 = -2.f * hh * d2;  k3 = 2.f * hh * d2 * cj.y;
    } else if (set == 1) {
        k0 = hh;  k1 = -2.f * hh * d1;  k2 = 2.f * hh * d1 * cj.x;  k3 = 0.f;
    } else {
        k0 = hh;  k1 = -2.f * hh * d2;  k2 = 2.f * hh * d2 * cj.y;  k3 = 0.f;
    }
    RA[idx] = make_float4(zb, zc, zd, ze);
    RB[idx] = make_float4(za, k0, k1, k2);
    RC[idx] = k3;
    RT[idx] = make_float4(cj.x, cj.y, d1 * LOG2E, d2 * LOG2E);
}

// K2: exclusive prefix sum over 256 cells (1 block).
__global__ __launch_bounds__(256) void prefix_kernel(
    const unsigned int* __restrict__ cnt, unsigned int* __restrict__ cursor)
{
    __shared__ unsigned int s[256];
    const int t = threadIdx.x;
    unsigned int v = cnt[t];
    s[t] = v;
    __syncthreads();
    unsigned int acc = v;
    for (int off = 1; off < 256; off <<= 1) {
        unsigned int y = (t >= off) ? s[t - off] : 0u;
        __syncthreads();
        acc += y; s[t] = acc;
        __syncthreads();
    }
    cursor[t] = acc - v;   // exclusive
}

// K3: scatter point indices into cell-sorted order.
__global__ __launch_bounds__(256) void scatter_kernel(
    const float* __restrict__ x, unsigned int* __restrict__ cursor,
    unsigned short* __restrict__ sortedIdx)
{
    const int i = blockIdx.x * 256 + threadIdx.x;
    float2 p = ((const float2*)x)[i];
    unsigned int slot = atomicAdd(&cursor[cell_of(p)], 1u);
    sortedIdx[slot] = (unsigned short)i;
}

// K4: per (slice,set): bbox of slice's 1024 points, cull 1024 centers,
// gather live constants CONTIGUOUSLY into GA/GB/GC (sequential s_load feed).
__global__ __launch_bounds__(256) void cull_kernel(
    const float* __restrict__ x,
    const float4* __restrict__ RA, const float4* __restrict__ RB,
    const float*  __restrict__ RC, const float4* __restrict__ RT,
    const unsigned short* __restrict__ sortedIdx,
    float4* __restrict__ GA, float4* __restrict__ GB, float* __restrict__ GC,
    int* __restrict__ mcount)
{
    __shared__ float4 bbx[4];
    __shared__ int    wtot[4];
    __shared__ int    runbase;

    const int bid   = blockIdx.x;      // 0..191
    const int slice = bid / 3;
    const int set   = bid % 3;
    const int tid   = threadIdx.x;
    const int lane  = tid & 63;
    const int wv    = tid >> 6;
    const int gb    = bid * N_CTR;

    // bbox over the slice's 1024 points
    float mnx = 1e9f, mxx = -1e9f, mny = 1e9f, mxy = -1e9f;
    const float2* xp = (const float2*)x;
    #pragma unroll
    for (int k = 0; k < 4; ++k) {
        int o = sortedIdx[slice * 1024 + k * 256 + tid];
        float2 p = xp[o];
        mnx = fminf(mnx, p.x); mxx = fmaxf(mxx, p.x);
        mny = fminf(mny, p.y); mxy = fmaxf(mxy, p.y);
    }
    #pragma unroll
    for (int d = 1; d < 64; d <<= 1) {
        mnx = fminf(mnx, __shfl_xor(mnx, d));
        mxx = fmaxf(mxx, __shfl_xor(mxx, d));
        mny = fminf(mny, __shfl_xor(mny, d));
        mxy = fmaxf(mxy, __shfl_xor(mxy, d));
    }
    if (tid == 0) runbase = 0;
    if (lane == 0) bbx[wv] = make_float4(mnx, mxx, mny, mxy);
    __syncthreads();
    {
        float4 b0 = bbx[0], b1 = bbx[1], b2 = bbx[2], b3 = bbx[3];
        mnx = fminf(fminf(b0.x, b1.x), fminf(b2.x, b3.x));
        mxx = fmaxf(fmaxf(b0.y, b1.y), fmaxf(b2.y, b3.y));
        mny = fminf(fminf(b0.z, b1.z), fminf(b2.z, b3.z));
        mxy = fmaxf(fmaxf(b0.w, b1.w), fmaxf(b2.w, b3.w));
    }

    // cull 4 batches of 256 centers; ordered compaction to global
    for (int b4 = 0; b4 < 4; ++b4) {
        const int j = set * N_CTR + b4 * 256 + tid;
        float4 T = RT[j];
        float dxm = fmaxf(fmaxf(mnx - T.x, T.x - mxx), 0.f);
        float dym = fmaxf(fmaxf(mny - T.y, T.y - mxy), 0.f);
        float qv  = dxm * dxm * T.z + dym * dym * T.w;
        const bool live = qv < CUT;
        unsigned long long mask = __ballot(live);
        if (lane == 0) wtot[wv] = __popcll(mask);
        __syncthreads();
        int pre = 0, tot = 0;
        #pragma unroll
        for (int w2 = 0; w2 < 4; ++w2) {
            int t = wtot[w2];
            if (w2 < wv) pre += t;
            tot += t;
        }
        const int b = runbase;
        if (live) {
            int pos = gb + b + pre + __popcll(mask & ((1ull << lane) - 1ull));
            GA[pos] = RA[j]; GB[pos] = RB[j]; GC[pos] = RC[j];
        }
        __syncthreads();
        if (tid == 0) runbase = b + tot;
        __syncthreads();
    }
    if (tid == 0) mcount[bid] = runbase;
}

// K5: main. Block = (slice, set, quarter). 1 point/thread, full live list,
// sequential uniform constant reads (s_load prefetch), direct stores.
__global__ __launch_bounds__(256) void srbf_main(
    const float* __restrict__ x,
    const float4* __restrict__ GA, const float4* __restrict__ GB,
    const float*  __restrict__ GC,
    const unsigned short* __restrict__ sortedIdx,
    const int* __restrict__ mcount,
    float* __restrict__ out)
{
    const int bid   = blockIdx.x;        // 0..767
    const int slice = bid / 12;
    const int rr    = bid % 12;
    const int set   = rr >> 2;
    const int q     = rr & 3;
    const int tid   = threadIdx.x;
    const int lb    = slice * 3 + set;
    const int gb    = lb * N_CTR;
    const int m     = mcount[lb];

    const int o = sortedIdx[slice * 1024 + q * 256 + tid];
    float2 p = ((const float2*)x)[o];
    const float X = p.x, Y = p.y;

    float A0 = 0.f, A1 = 0.f, A2 = 0.f, A3 = 0.f;

    if (set == 0) {
        #pragma unroll 4
        for (int t = 0; t < m; ++t) {
            const float4 A  = GA[gb + t];   // uniform sequential -> s_load
            const float4 K  = GB[gb + t];
            const float  k3 = GC[gb + t];
            float u1 = fmaf(X, A.y, A.x);
            float u2 = fmaf(X, u1,  K.x);
            float u3 = fmaf(Y, A.w, A.z);
            float s  = fmaf(Y, u3,  u2);
            float e  = EXP2(s);
            A0 = fmaf(K.y, e, A0);
            A1 = fmaf(K.z, e, A1);
            A2 = fmaf(K.w, e, A2);
            A3 = fmaf(k3,  e, A3);
        }
    } else {
        #pragma unroll 4
        for (int t = 0; t < m; ++t) {
            const float4 A = GA[gb + t];
            const float4 K = GB[gb + t];
            float u1 = fmaf(X, A.y, A.x);
            float u2 = fmaf(X, u1,  K.x);
            float u3 = fmaf(Y, A.w, A.z);
            float s  = fmaf(Y, u3,  u2);
            float e  = EXP2(s);
            A0 = fmaf(K.y, e, A0);
            A1 = fmaf(K.z, e, A1);
            A2 = fmaf(K.w, e, A2);
        }
    }

    float* ob = out + (size_t)set * 2 * N_PTS;
    float r1, r2;
    if (set == 0)      { r1 = fmaf(X, A0, A1); r2 = fmaf(Y, A2, A3); }
    else if (set == 1) { r1 = A0;              r2 = fmaf(X, A1, A2); }
    else               { r1 = A0;              r2 = fmaf(Y, A1, A2); }
    ob[o]         = r1;   // complete sum per (point,set): direct store
    ob[N_PTS + o] = r2;
}

extern "C" void kernel_launch(void* const* d_in, const int* in_sizes, int n_in,
                              void* d_out, int out_size, void* d_ws, size_t ws_size,
                              hipStream_t stream) {
    const float* x  = (const float*)d_in[0];
    const float* h1 = (const float*)d_in[1];
    const float* c1 = (const float*)d_in[2];
    const float* w1 = (const float*)d_in[3];
    const float* h2 = (const float*)d_in[4];
    const float* c2 = (const float*)d_in[5];
    const float* w2 = (const float*)d_in[6];
    const float* h3 = (const float*)d_in[7];
    const float* c3 = (const float*)d_in[8];
    const float* w3 = (const float*)d_in[9];

    char* ws = (char*)d_ws;
    float4* RA = (float4*)(ws);                              // 49152 B
    float4* RB = (float4*)(ws + 49152);                      // 49152 B
    float*  RC = (float*) (ws + 98304);                      // 12288 B
    float4* RT = (float4*)(ws + 110592);                     // 49152 B
    unsigned int*   cnt    = (unsigned int*)(ws + 159744);   // 1024 B
    unsigned int*   cursor = (unsigned int*)(ws + 160768);   // 1024 B
    unsigned short* sidx   = (unsigned short*)(ws + 161792); // 131072 B -> ends 292864
    float4* GA = (float4*)(ws + 292864);                     // 192*1024*16 = 3145728
    float4* GB = (float4*)(ws + 3438592);                    // 3145728
    float*  GC = (float*) (ws + 6584320);                    // 786432
    int*    mcount = (int*)(ws + 7370752);                   // 768 B (total ~7.37 MB)

    hipMemsetAsync(cnt, 0, NCELLS * sizeof(unsigned int), stream);

    // K1: constants + per-cell counts
    prep_kernel<<<dim3(256), dim3(256), 0, stream>>>(
        x, h1, c1, w1, h2, c2, w2, h3, c3, w3, RA, RB, RC, RT, cnt);

    // K2: prefix sum -> cursor
    prefix_kernel<<<dim3(1), dim3(256), 0, stream>>>(cnt, cursor);

    // K3: scatter to sorted order
    scatter_kernel<<<dim3(256), dim3(256), 0, stream>>>(x, cursor, sidx);

    // K4: per (slice,set) cull + contiguous gather of live constants
    cull_kernel<<<dim3(NSLICE * 3), dim3(256), 0, stream>>>(
        x, RA, RB, RC, RT, sidx, GA, GB, GC, mcount);

    // K5: 64 slices x 3 sets x 4 quarters = 768 blocks (3/CU exact)
    srbf_main<<<dim3(768), dim3(256), 0, stream>>>(
        x, GA, GB, GC, sidx, mcount, (float*)d_out);
}

// Round 11
// 52.270 us; speedup vs baseline: 3.0716x; 3.0716x over previous
//
#include <hip/hip_runtime.h>
#include <math.h>

#define N_PTS  65536
#define N_CTR  1024
#define CHUNK  128          // centers per block -> 8 chunks per set
#define PPT    4            // points per thread
#define PPB    (256 * PPT)  // 1024 points per block
#define LOG2E  1.4426950408889634f

#if __has_builtin(__builtin_amdgcn_exp2f)
#define EXP2(v) __builtin_amdgcn_exp2f(v)
#else
#define EXP2(v) exp2f(v)
#endif

// Dense schedule, tuned from R4 (best verified: 52.8us main @78% VALUBusy):
//  - constants staged in LDS -> uniform broadcast ds_reads land in VGPRs,
//    every FMA is v*v+v (no s_load SGPR-operand fixup movs, no SMEM chain)
//  - compile-time 128-iteration loop, unroll 4 (pipelineable)
//  - PPT=4: state ~40 VGPR, no rematerialization (R2's PPT=8 remat bug)
//  - grid 1536 = 6 blocks/CU, no launch_bounds cap (8-resident headroom)
//  - constants folded inline at block start (no prep kernel; 2 dispatches)
// Horner: s = (za + x*(zb+zc*x)) + y*(zd+ze*y); e = exp2(s)
// set0: ux = x*S(k0 e)+S(k1 e), uy = y*S(k2 e)+S(k3 e)
// set1: P = S(k0 e), Px = x*S(k1 e)+S(k2 e);  set2: Q,Qy analog.
__global__ __launch_bounds__(256) void srbf_main(
    const float* __restrict__ x,
    const float* __restrict__ h0, const float* __restrict__ c0, const float* __restrict__ w0,
    const float* __restrict__ h1, const float* __restrict__ c1, const float* __restrict__ w1,
    const float* __restrict__ h2, const float* __restrict__ c2, const float* __restrict__ w2,
    float* __restrict__ out)
{
    __shared__ float4 sA[CHUNK];   // (za, zb, zc, ...) -> (zb, zc, zd, ze)
    __shared__ float4 sK[CHUNK];   // (za, k0, k1, k2)
    __shared__ float  sk3[CHUNK];  // k3

    const int bid   = blockIdx.x;        // 0..1535
    const int set   = bid >> 9;          // 512 blocks per set
    const int r     = bid & 511;
    const int chunk = r >> 6;            // 8 chunks of 128 centers
    const int pblk  = r & 63;            // 64 point-blocks of 1024 points
    const int tid   = threadIdx.x;

    // ---- inline constant fold: 128 threads, one center each ----
    if (tid < CHUNK) {
        const int j = chunk * CHUNK + tid;
        const float*  h = (set == 0) ? h0 : ((set == 1) ? h1 : h2);
        const float2* c = (const float2*)((set == 0) ? c0 : ((set == 1) ? c1 : c2));
        const float2* w = (const float2*)((set == 0) ? w0 : ((set == 1) ? w1 : w2));
        float2 cj = c[j];
        float2 wj = w[j];
        float  hh = h[j];
        float d1 = wj.x * wj.x;
        float d2 = wj.y * wj.y;
        float zb =  2.f * cj.x * d1 * LOG2E;
        float zc = -d1 * LOG2E;
        float zd =  2.f * cj.y * d2 * LOG2E;
        float ze = -d2 * LOG2E;
        float za = -(cj.x * cj.x * d1 + cj.y * cj.y * d2) * LOG2E;
        float k0, k1, k2, k3;
        if (set == 0) {
            k0 = -2.f * hh * d1;  k1 = 2.f * hh * d1 * cj.x;
            k2 = -2.f * hh * d2;  k3 = 2.f * hh * d2 * cj.y;
        } else if (set == 1) {
            k0 = hh;  k1 = -2.f * hh * d1;  k2 = 2.f * hh * d1 * cj.x;  k3 = 0.f;
        } else {
            k0 = hh;  k1 = -2.f * hh * d2;  k2 = 2.f * hh * d2 * cj.y;  k3 = 0.f;
        }
        sA[tid]  = make_float4(zb, zc, zd, ze);
        sK[tid]  = make_float4(za, k0, k1, k2);
        sk3[tid] = k3;
    }

    // ---- load 4 points while constants fold ----
    const int base = pblk * PPB + tid;
    float X[PPT], Y[PPT];
    #pragma unroll
    for (int p = 0; p < PPT; ++p) {
        float2 q = ((const float2*)x)[base + p * 256];
        X[p] = q.x;  Y[p] = q.y;
    }
    __syncthreads();

    if (set == 0) {
        float A0[PPT], A1[PPT], A2[PPT], A3[PPT];
        #pragma unroll
        for (int p = 0; p < PPT; ++p) { A0[p] = A1[p] = A2[p] = A3[p] = 0.f; }

        #pragma unroll 4
        for (int j = 0; j < CHUNK; ++j) {
            const float4 A  = sA[j];    // broadcast ds_read -> VGPRs
            const float4 K  = sK[j];
            const float  k3 = sk3[j];
            float e[PPT];
            #pragma unroll
            for (int p = 0; p < PPT; ++p) {
                float t1 = fmaf(X[p], A.y, A.x);   // zb + zc*x
                float t2 = fmaf(X[p], t1,  K.x);   // za + x*(...)
                float t3 = fmaf(Y[p], A.w, A.z);   // zd + ze*y
                float s  = fmaf(Y[p], t3,  t2);
                e[p] = EXP2(s);
            }
            #pragma unroll
            for (int p = 0; p < PPT; ++p) {
                A0[p] = fmaf(K.y, e[p], A0[p]);
                A1[p] = fmaf(K.z, e[p], A1[p]);
                A2[p] = fmaf(K.w, e[p], A2[p]);
                A3[p] = fmaf(k3,  e[p], A3[p]);
            }
        }
        #pragma unroll
        for (int p = 0; p < PPT; ++p) {
            const int i = base + p * 256;
            atomicAdd(&out[i],         fmaf(X[p], A0[p], A1[p]));   // ux
            atomicAdd(&out[N_PTS + i], fmaf(Y[p], A2[p], A3[p]));   // uy
        }
    } else {
        float A0[PPT], A1[PPT], A2[PPT];
        #pragma unroll
        for (int p = 0; p < PPT; ++p) { A0[p] = A1[p] = A2[p] = 0.f; }

        #pragma unroll 4
        for (int j = 0; j < CHUNK; ++j) {
            const float4 A = sA[j];
            const float4 K = sK[j];
            float e[PPT];
            #pragma unroll
            for (int p = 0; p < PPT; ++p) {
                float t1 = fmaf(X[p], A.y, A.x);
                float t2 = fmaf(X[p], t1,  K.x);
                float t3 = fmaf(Y[p], A.w, A.z);
                float s  = fmaf(Y[p], t3,  t2);
                e[p] = EXP2(s);
            }
            #pragma unroll
            for (int p = 0; p < PPT; ++p) {
                A0[p] = fmaf(K.y, e[p], A0[p]);
                A1[p] = fmaf(K.z, e[p], A1[p]);
                A2[p] = fmaf(K.w, e[p], A2[p]);
            }
        }
        float* o = out + (size_t)set * 2 * N_PTS;
        #pragma unroll
        for (int p = 0; p < PPT; ++p) {
            const int i = base + p * 256;
            const float g = (set == 1) ? X[p] : Y[p];
            atomicAdd(&o[i],         A0[p]);                  // P or Q
            atomicAdd(&o[N_PTS + i], fmaf(g, A1[p], A2[p]));  // Px or Qy
        }
    }
}

extern "C" void kernel_launch(void* const* d_in, const int* in_sizes, int n_in,
                              void* d_out, int out_size, void* d_ws, size_t ws_size,
                              hipStream_t stream) {
    const float* x  = (const float*)d_in[0];
    const float* h1 = (const float*)d_in[1];
    const float* c1 = (const float*)d_in[2];
    const float* w1 = (const float*)d_in[3];
    const float* h2 = (const float*)d_in[4];
    const float* c2 = (const float*)d_in[5];
    const float* w2 = (const float*)d_in[6];
    const float* h3 = (const float*)d_in[7];
    const float* c3 = (const float*)d_in[8];
    const float* w3 = (const float*)d_in[9];

    hipMemsetAsync(d_out, 0, (size_t)out_size * sizeof(float), stream);

    // 3 sets x 8 center-chunks x 64 point-blocks = 1536 blocks (6/CU)
    srbf_main<<<dim3(1536), dim3(256), 0, stream>>>(
        x, h1, c1, w1, h2, c2, w2, h3, c3, w3, (float*)d_out);
}